// Round 3
// baseline (1021.854 us; speedup 1.0000x reference)
//
#include <hip/hip_runtime.h>
#include <hip/hip_fp16.h>

#define H_A   2048
#define H_HP  4096
#define DEPTH 12
#define KCOMB 2304   // 256 (a) + 2048 (h_a): combined K for the arch-gate GEMV

typedef _Float16 f16x8 __attribute__((ext_vector_type(8)));
typedef float    f32x4 __attribute__((ext_vector_type(4)));

struct Half8 { __half2 a, b, c, d; };   // 16 B
struct Half4 { __half2 a, b; };         // 8 B

__device__ __forceinline__ float fsig_(float x) { return 1.0f / (1.0f + __expf(-x)); }
__device__ __forceinline__ float ftanh_(float x) {
    return 1.0f - 2.0f / (__expf(2.0f * x) + 1.0f);
}
__device__ __forceinline__ float dot4_(float4 a, float4 b) {
    return a.x * b.x + a.y * b.y + a.z * b.z + a.w * b.w;
}
__device__ __forceinline__ float dot8h_(Half8 w, float4 x0, float4 x1) {
    float2 wa = __half22float2(w.a), wb = __half22float2(w.b);
    float2 wc = __half22float2(w.c), wd = __half22float2(w.d);
    return wa.x * x0.x + wa.y * x0.y + wb.x * x0.z + wb.y * x0.w +
           wc.x * x1.x + wc.y * x1.y + wd.x * x1.z + wd.y * x1.w;
}
__device__ __forceinline__ Half4 cvt4_(float4 a) {
    Half4 h;
    h.a = __floats2half2_rn(a.x, a.y);
    h.b = __floats2half2_rn(a.z, a.w);
    return h;
}
__device__ __forceinline__ Half8 cvt8_(float4 a, float4 b) {
    Half8 h;
    h.a = __floats2half2_rn(a.x, a.y);
    h.b = __floats2half2_rn(a.z, a.w);
    h.c = __floats2half2_rn(b.x, b.y);
    h.d = __floats2half2_rn(b.z, b.w);
    return h;
}
__device__ __forceinline__ f16x8 cvtf8_(float4 a, float4 b) {
    f16x8 r;
    r[0] = (_Float16)a.x; r[1] = (_Float16)a.y; r[2] = (_Float16)a.z; r[3] = (_Float16)a.w;
    r[4] = (_Float16)b.x; r[5] = (_Float16)b.y; r[6] = (_Float16)b.z; r[7] = (_Float16)b.w;
    return r;
}
__device__ __forceinline__ float waveReduceSum(float v) {
#pragma unroll
    for (int off = 32; off > 0; off >>= 1) v += __shfl_xor(v, off, 64);
    return v;
}
__device__ __forceinline__ void waveReduce4(float& a0, float& a1, float& a2, float& a3) {
#pragma unroll
    for (int off = 32; off > 0; off >>= 1) {
        a0 += __shfl_xor(a0, off, 64);
        a1 += __shfl_xor(a1, off, 64);
        a2 += __shfl_xor(a2, off, 64);
        a3 += __shfl_xor(a3, off, 64);
    }
}

struct Params {
    const float *x_a, *x_hp;
    const float *W_ih_a, *W_hh_a, *b_ih_a, *b_hh_a;
    const float *W_out_a, *b_out_a, *W_sum, *b_sum;
    const float *W_ih_hp, *W_hh_hp, *b_ih_hp, *b_hh_hp, *W_out_hp, *b_out_hp;
    // fragment-tiled fp16 (16 rows x 32 k per 1 KiB tile, lane-major) for MFMA GEMVs:
    __half *hW_a, *hW_sum, *hW_hh_hp, *hW_out_hp;
    // row-major fp16 (kC / kB scalar paths, unchanged):
    __half *hW_ih_hp, *hW_out_a;
    // fp16 x vectors for MFMA B operand: xa_h = [a(256) | h_a(2048)]
    __half *xa_h, *hhp_h, *chp_h;
    float *gates_a, *h_sum, *gacc, *h_a, *c_a0, *c_a1, *h_hp, *c_hp;
    float *logits_a, *logits_hp, *out;
};

// ===========================================================================
// kA — all big GEMVs via MFMA. 1680 blocks x 256 threads, one 16-row output
// tile per block, 4 waves split K, LDS reduce.
//   blocks [0,512):     gates_a  (8192 rows, K=2304, x=[a|h_a])
//   blocks [512,640):   h_sum    (2048 rows, K=4096, x=h_hp)
//   blocks [640,1664):  gacc     (16384 rows, K=4096, x=c_hp)
//   blocks [1664,1680): logits_hp(t-1) (256 rows, K=4096, x=h_hp), skip t==0
// t==0: fragment-gather fp32 read -> convert+store fragment-tiled fp16; exact
// fp32 dot for gates_a / h_sum (initial state); gacc = bias only (c_hp=0).
// t>=1: A = 1 KiB weight tile (coalesced lane*16B), B = x broadcast into all
// 16 cols; D row mapping (lane>>4)*4+reg gives the 16 row sums.
// ===========================================================================
__global__ __launch_bounds__(256) void kA(Params p, int t)
{
    __shared__ float red[4][16];
    const int tid = threadIdx.x, lane = tid & 63, wv = tid >> 6;
    const int b = blockIdx.x;

    int sec, rb, ntiles;
    __half* Wf; const __half* xh;
    if (b < 512)       { sec = 0; rb = b;        Wf = p.hW_a      + (size_t)rb * 16 * KCOMB; xh = p.xa_h;  ntiles = KCOMB / 32; }
    else if (b < 640)  { sec = 1; rb = b - 512;  Wf = p.hW_sum    + (size_t)rb * 16 * H_HP;  xh = p.hhp_h; ntiles = H_HP / 32; }
    else if (b < 1664) { sec = 2; rb = b - 640;  Wf = p.hW_hh_hp  + (size_t)rb * 16 * H_HP;  xh = p.chp_h; ntiles = H_HP / 32; }
    else               { sec = 3; rb = b - 1664; Wf = p.hW_out_hp + (size_t)rb * 16 * H_HP;  xh = p.hhp_h; ntiles = H_HP / 32; }
    const int ntl = ntiles >> 2;       // tiles per wave (18 or 32, both even)
    const int kt0 = wv * ntl;

    if (t > 0) {
        f32x4 acc0 = {0.f, 0.f, 0.f, 0.f}, acc1 = {0.f, 0.f, 0.f, 0.f};
        const int xoff = (lane >> 4) * 8;
#pragma unroll 2
        for (int i = 0; i < ntl; i += 2) {
            const int kt = kt0 + i;
            f16x8 a0 = *(const f16x8*)(Wf + (size_t)kt * 512 + lane * 8);
            f16x8 b0 = *(const f16x8*)(xh + kt * 32 + xoff);
            f16x8 a1 = *(const f16x8*)(Wf + (size_t)(kt + 1) * 512 + lane * 8);
            f16x8 b1 = *(const f16x8*)(xh + (kt + 1) * 32 + xoff);
            acc0 = __builtin_amdgcn_mfma_f32_16x16x32_f16(a0, b0, acc0, 0, 0, 0);
            acc1 = __builtin_amdgcn_mfma_f32_16x16x32_f16(a1, b1, acc1, 0, 0, 0);
        }
        f32x4 acc = acc0 + acc1;
        if ((lane & 15) == 0) {
            const int r0 = (lane >> 4) * 4;
            red[wv][r0]     = acc[0];
            red[wv][r0 + 1] = acc[1];
            red[wv][r0 + 2] = acc[2];
            red[wv][r0 + 3] = acc[3];
        }
    } else {
        // t == 0: convert fp32 -> fragment-tiled fp16 (+ exact fp32 dot for sec 0/1)
        float ppart = 0.0f;
        const int row = rb * 16 + (lane & 15);
        const int kc = (lane >> 4) * 8;
        for (int i = 0; i < ntl; ++i) {
            const int kt = kt0 + i;
            const int k = kt * 32 + kc;
            const float* src;
            if (sec == 0)      src = (k < 256) ? p.W_ih_a + (size_t)row * 256 + k
                                               : p.W_hh_a + (size_t)row * H_A + (k - 256);
            else if (sec == 1) src = p.W_sum    + (size_t)row * H_HP + k;
            else if (sec == 2) src = p.W_hh_hp  + (size_t)row * H_HP + k;
            else               src = p.W_out_hp + (size_t)row * H_HP + k;
            float4 u = ((const float4*)src)[0];
            float4 v = ((const float4*)src)[1];
            *(f16x8*)(Wf + (size_t)kt * 512 + lane * 8) = cvtf8_(u, v);
            if (sec == 0) {
                if (k < 256) {
                    ppart += (u.x + u.y + u.z + u.w + v.x + v.y + v.z + v.w) * (1.0f / 256.0f);
                } else {
                    float4 xu = *(const float4*)(p.x_a + (k - 256));
                    float4 xv = *(const float4*)(p.x_a + (k - 256) + 4);
                    ppart += dot4_(u, xu) + dot4_(v, xv);
                }
            } else if (sec == 1) {
                float4 xu = *(const float4*)(p.x_hp + k);
                float4 xv = *(const float4*)(p.x_hp + k + 4);
                ppart += dot4_(u, xu) + dot4_(v, xv);
            }
        }
        ppart += __shfl_xor(ppart, 16, 64);
        ppart += __shfl_xor(ppart, 32, 64);
        if (lane < 16) red[wv][lane] = ppart;
    }

    __syncthreads();
    if (tid < 16) {
        const int g = rb * 16 + tid;
        float s = 0.0f;
        if (t > 0 || sec <= 1)
            s = red[0][tid] + red[1][tid] + red[2][tid] + red[3][tid];
        if (sec == 0)      p.gates_a[g] = s + p.b_ih_a[g] + p.b_hh_a[g];
        else if (sec == 1) p.h_sum[g]   = fmaxf(s + p.b_sum[g], 0.0f);
        else if (sec == 2) p.gacc[g]    = s + p.b_ih_hp[g] + p.b_hh_hp[g];   // t==0: bias only
        else if (t > 0)    p.logits_hp[g] = s + p.b_out_hp[g];
    }
}

// ===========================================================================
// kB: arch pointwise LSTM (redundant per block, h into LDS) + W_out_a GEMV.
// 64 blocks x 256 threads -> 256 rows (one per wave). Block 0 writes state
// (fp32 + the fp16 copy kA's MFMA B-operand needs).
// ===========================================================================
__global__ __launch_bounds__(256) void kB(Params p, int t)
{
    __shared__ float h_s[H_A];
    const int tid = threadIdx.x;
    const float* cin = (t & 1) ? p.c_a1 : p.c_a0;
    float* cout = (t & 1) ? p.c_a0 : p.c_a1;
#pragma unroll
    for (int k = 0; k < 8; ++k) {
        int e = tid + k * 256;
        float gi = p.gates_a[e], gf = p.gates_a[H_A + e];
        float gg = p.gates_a[2 * H_A + e], go = p.gates_a[3 * H_A + e];
        float ci = (t == 0) ? 0.0f : cin[e];
        float c = fsig_(gf) * ci + fsig_(gi) * ftanh_(gg);
        float h = fsig_(go) * ftanh_(c);
        h_s[e] = h;
        if (blockIdx.x == 0) {
            cout[e] = c;
            p.h_a[e] = h;
            p.xa_h[256 + e] = __float2half(h);
        }
    }
    __syncthreads();
    const int lane = tid & 63;
    const int r = (blockIdx.x << 2) | (tid >> 6);
    const float4* h4 = (const float4*)h_s;
    float acc = 0.0f;
    if (t == 0) {
        const float4* wf = (const float4*)(p.W_out_a + (size_t)r * H_A);
        Half4* dsth = (Half4*)(p.hW_out_a + (size_t)r * H_A);
#pragma unroll
        for (int it = 0; it < 8; ++it) {
            int idx = it * 64 + lane;
            float4 w = wf[idx];
            dsth[idx] = cvt4_(w);
            acc += dot4_(w, h4[idx]);
        }
    } else {
        const Half8* ww = (const Half8*)(p.hW_out_a + (size_t)r * H_A);
#pragma unroll
        for (int it = 0; it < 4; ++it) {
            int idx = it * 64 + lane;
            acc += dot8h_(ww[idx], h4[2 * idx], h4[2 * idx + 1]);
        }
    }
    acc = waveReduceSum(acc);
    if (lane == 0) p.logits_a[r] = acc + p.b_out_a[r];
}

// ===========================================================================
// kC: block-redundant dual softmax (a(t); a_hp(t-1) — t==0 logits 0 -> 1/256)
// + W_ih_hp GEMV + hp pointwise LSTM (reference's swapped states).
// 1024 blocks x 256 threads. Block 0 writes a outputs + fp16 a; each wave's
// lane 0 writes h_hp/c_hp (fp32 + fp16 copies for kA's MFMA).
// ===========================================================================
__global__ __launch_bounds__(256) void kC(Params p, int t)
{
    __shared__ float p_all[512];
    __shared__ float red[8];
    const int tid = threadIdx.x, lane = tid & 63, wv = tid >> 6;
    float la = p.logits_a[tid];
    float lh = (t == 0) ? 0.0f : p.logits_hp[tid];
    float ma = la, mh = lh;
#pragma unroll
    for (int off = 32; off > 0; off >>= 1) {
        ma = fmaxf(ma, __shfl_xor(ma, off, 64));
        mh = fmaxf(mh, __shfl_xor(mh, off, 64));
    }
    if (lane == 0) { red[wv] = ma; red[4 + wv] = mh; }
    __syncthreads();
    ma = fmaxf(fmaxf(red[0], red[1]), fmaxf(red[2], red[3]));
    mh = fmaxf(fmaxf(red[4], red[5]), fmaxf(red[6], red[7]));
    __syncthreads();
    float ea = __expf(la - ma), eh = __expf(lh - mh);
    float sa = waveReduceSum(ea), sh = waveReduceSum(eh);
    if (lane == 0) { red[wv] = sa; red[4 + wv] = sh; }
    __syncthreads();
    sa = red[0] + red[1] + red[2] + red[3];
    sh = red[4] + red[5] + red[6] + red[7];
    float pa = ea / sa, ph = eh / sh;
    p_all[tid] = pa;
    p_all[256 + tid] = ph;
    if (blockIdx.x == 0) {
        p.xa_h[tid] = __float2half(pa);
        p.out[(size_t)t * 256 + tid] = pa;                          // out_a[t]
        if (t > 0) p.out[3072 + (size_t)(t - 1) * 256 + tid] = ph;  // out_hp[t-1]
    }
    __syncthreads();
    float4 xa = ((const float4*)p_all)[2 * lane];
    float4 xb = ((const float4*)p_all)[2 * lane + 1];
    const int e = (blockIdx.x << 2) | wv;   // 0..4095
    float s0, s1, s2, s3;
    if (t == 0) {
        auto rowdot_cvt = [&](int r) -> float {
            const float4* wf = (const float4*)(p.W_ih_hp + (size_t)r * 512);
            float4 u = wf[2 * lane], v = wf[2 * lane + 1];
            ((Half8*)(p.hW_ih_hp + (size_t)r * 512))[lane] = cvt8_(u, v);
            return dot4_(u, xa) + dot4_(v, xb);
        };
        s0 = rowdot_cvt(e);
        s1 = rowdot_cvt(4096 + e);
        s2 = rowdot_cvt(8192 + e);
        s3 = rowdot_cvt(12288 + e);
    } else {
        Half8 w0 = ((const Half8*)(p.hW_ih_hp + (size_t)e * 512))[lane];
        Half8 w1 = ((const Half8*)(p.hW_ih_hp + (size_t)(4096 + e) * 512))[lane];
        Half8 w2 = ((const Half8*)(p.hW_ih_hp + (size_t)(8192 + e) * 512))[lane];
        Half8 w3 = ((const Half8*)(p.hW_ih_hp + (size_t)(12288 + e) * 512))[lane];
        s0 = dot8h_(w0, xa, xb);
        s1 = dot8h_(w1, xa, xb);
        s2 = dot8h_(w2, xa, xb);
        s3 = dot8h_(w3, xa, xb);
    }
    waveReduce4(s0, s1, s2, s3);
    if (lane == 0) {
        float gi = s0 + p.gacc[e];
        float gf = s1 + p.gacc[4096 + e];
        float gg = s2 + p.gacc[8192 + e];
        float go = s3 + p.gacc[12288 + e];
        float prev = (e < H_A) ? p.h_a[e] : p.h_sum[e - H_A];
        float c = fsig_(gf) * prev + fsig_(gi) * ftanh_(gg);
        float h = fsig_(go) * ftanh_(c);
        p.c_hp[e] = c;
        p.h_hp[e] = h;
        p.chp_h[e] = __float2half(c);
        p.hhp_h[e] = __float2half(h);
    }
}

// ===========================================================================
// tail: logits_hp(11) = W_out_hp·h_hp(11) via MFMA (16 blocks), then softmax.
// ===========================================================================
__global__ __launch_bounds__(256) void kTail_gemv(Params p)
{
    __shared__ float red[4][16];
    const int tid = threadIdx.x, lane = tid & 63, wv = tid >> 6;
    const int rb = blockIdx.x;
    const __half* Wf = p.hW_out_hp + (size_t)rb * 16 * H_HP;
    const __half* xh = p.hhp_h;
    const int kt0 = wv * 32;
    f32x4 acc0 = {0.f, 0.f, 0.f, 0.f}, acc1 = {0.f, 0.f, 0.f, 0.f};
    const int xoff = (lane >> 4) * 8;
#pragma unroll 2
    for (int i = 0; i < 32; i += 2) {
        const int kt = kt0 + i;
        f16x8 a0 = *(const f16x8*)(Wf + (size_t)kt * 512 + lane * 8);
        f16x8 b0 = *(const f16x8*)(xh + kt * 32 + xoff);
        f16x8 a1 = *(const f16x8*)(Wf + (size_t)(kt + 1) * 512 + lane * 8);
        f16x8 b1 = *(const f16x8*)(xh + (kt + 1) * 32 + xoff);
        acc0 = __builtin_amdgcn_mfma_f32_16x16x32_f16(a0, b0, acc0, 0, 0, 0);
        acc1 = __builtin_amdgcn_mfma_f32_16x16x32_f16(a1, b1, acc1, 0, 0, 0);
    }
    f32x4 acc = acc0 + acc1;
    if ((lane & 15) == 0) {
        const int r0 = (lane >> 4) * 4;
        red[wv][r0]     = acc[0];
        red[wv][r0 + 1] = acc[1];
        red[wv][r0 + 2] = acc[2];
        red[wv][r0 + 3] = acc[3];
    }
    __syncthreads();
    if (tid < 16) {
        const int g = rb * 16 + tid;
        p.logits_hp[g] = red[0][tid] + red[1][tid] + red[2][tid] + red[3][tid] + p.b_out_hp[g];
    }
}

__global__ __launch_bounds__(256) void kTail_softmax(Params p)
{
    __shared__ float red[4];
    const int tid = threadIdx.x, lane = tid & 63, wv = tid >> 6;
    float v = p.logits_hp[tid];
    float m = v;
#pragma unroll
    for (int off = 32; off > 0; off >>= 1) m = fmaxf(m, __shfl_xor(m, off, 64));
    if (lane == 0) red[wv] = m;
    __syncthreads();
    m = fmaxf(fmaxf(red[0], red[1]), fmaxf(red[2], red[3]));
    __syncthreads();
    float e = __expf(v - m);
    float s = waveReduceSum(e);
    if (lane == 0) red[wv] = s;
    __syncthreads();
    s = red[0] + red[1] + red[2] + red[3];
    p.out[3072 + 11 * 256 + tid] = e / s;
}

// ---------------------------------------------------------------------------

extern "C" void kernel_launch(void* const* d_in, const int* in_sizes, int n_in,
                              void* d_out, int out_size, void* d_ws, size_t ws_size,
                              hipStream_t stream)
{
    Params p;
    p.x_a      = (const float*)d_in[0];
    p.x_hp     = (const float*)d_in[1];
    p.W_ih_a   = (const float*)d_in[2];
    p.W_hh_a   = (const float*)d_in[3];
    p.b_ih_a   = (const float*)d_in[4];
    p.b_hh_a   = (const float*)d_in[5];
    p.W_out_a  = (const float*)d_in[6];
    p.b_out_a  = (const float*)d_in[7];
    p.W_sum    = (const float*)d_in[8];
    p.b_sum    = (const float*)d_in[9];
    p.W_ih_hp  = (const float*)d_in[10];
    p.W_hh_hp  = (const float*)d_in[11];
    p.b_ih_hp  = (const float*)d_in[12];
    p.b_hh_hp  = (const float*)d_in[13];
    p.W_out_hp = (const float*)d_in[14];
    p.b_out_hp = (const float*)d_in[15];

    // ws layout: fp16 weights (fragment-tiled first), then fp16 x, then fp32 state
    p.hW_a      = (__half*)d_ws;                     // 18,874,368 halves (8192 x 2304)
    p.hW_sum    = p.hW_a      + 18874368;            //  8,388,608 (2048 x 4096)
    p.hW_hh_hp  = p.hW_sum    + 8388608;             // 67,108,864 (16384 x 4096)
    p.hW_out_hp = p.hW_hh_hp  + 67108864;            //  1,048,576 (256 x 4096)
    p.hW_ih_hp  = p.hW_out_hp + 1048576;             //  8,388,608 (row-major, kC)
    p.hW_out_a  = p.hW_ih_hp  + 8388608;             //    524,288 (row-major, kB)
    p.xa_h      = p.hW_out_a  + 524288;              //      2,304 [a | h_a]
    p.hhp_h     = p.xa_h      + 2304;                //      4,096
    p.chp_h     = p.hhp_h     + 4096;                //      4,096
    float* ws   = (float*)(p.chp_h + 4096);

    p.gates_a   = ws;           // 8192
    p.h_sum     = ws + 8192;    // 2048
    p.gacc      = ws + 10240;   // 16384
    p.h_a       = ws + 26624;   // 2048
    p.c_a0      = ws + 28672;   // 2048
    p.c_a1      = ws + 30720;   // 2048
    p.h_hp      = ws + 32768;   // 4096
    p.c_hp      = ws + 36864;   // 4096
    p.logits_a  = ws + 40960;   // 256
    p.logits_hp = ws + 41216;   // 256
    p.out       = (float*)d_out;

    for (int t = 0; t < DEPTH; ++t) {
        kA<<<1680, 256, 0, stream>>>(p, t);
        kB<<<64, 256, 0, stream>>>(p, t);
        kC<<<1024, 256, 0, stream>>>(p, t);
    }
    kTail_gemv<<<16, 256, 0, stream>>>(p);
    kTail_softmax<<<1, 256, 0, stream>>>(p);
}